// Round 1
// baseline (19392.720 us; speedup 1.0000x reference)
//
#include <hip/hip_runtime.h>
#include <stdint.h>

// Seq2seq GRU encoder + greedy GRU decoder, single persistent cooperative kernel.
// 256 blocks x 256 threads; block b owns hidden units j in [4b, 4b+4), wave q -> j=4b+q.
// GRU weights stay f32 (argmax stability); lin_w converted to bf16 in ws for the
// per-step logits stream, with exact-f32 re-check of near-max rows for argmax.

#define HID 1024
#define SRC_LEN 256
#define MAX_LEN 128
#define VOC 32000
#define EOS_TOK 2u

#define NBLK 256
#define NTHR 256
#define RPB 125            // vocab rows per block = 32000/256

// ---- workspace layout (bytes) ----
#define WS_GCNT   0        // 8 group counters, 128B apart (0..896)
#define WS_G2     1024     // level-2 counter
#define WS_GEN    1152     // generation (separate line)
#define WS_GSUM   2048     // u64[128] fixed-point softmax sums
#define WS_GKEY   3072     // u64[128] argmax keys
#define WS_HB     4096     // float[2][1024] double-buffered h
#define WS_EXP    12288    // float[32000] exp(logit)
#define WS_ZERO   12288    // bytes to memset each call
#define WS_LINBF  141312   // ushort[32000*1024] bf16 lin_w
#define WS_NEED_BF (141312ull + (unsigned long long)VOC * HID * 2ull)

__device__ inline unsigned short f2bf(float f) {
  unsigned u = __float_as_uint(f);
  unsigned r = ((u >> 16) & 1u) + 0x7FFFu;   // round-to-nearest-even
  return (unsigned short)((u + r) >> 16);
}
__device__ inline float bflo(unsigned u) { return __uint_as_float(u << 16); }
__device__ inline float bfhi(unsigned u) { return __uint_as_float(u & 0xFFFF0000u); }
__device__ inline float sigm(float x) { return 1.0f / (1.0f + __expf(-x)); }

// two-level sense barrier: 8 groups of 32 blocks
__device__ inline void grid_bar(char* ws) {
  __syncthreads();
  if (threadIdx.x == 0) {
    unsigned* gen = (unsigned*)(ws + WS_GEN);
    __threadfence();
    unsigned g = __hip_atomic_load(gen, __ATOMIC_RELAXED, __HIP_MEMORY_SCOPE_AGENT);
    unsigned* gc = (unsigned*)(ws + WS_GCNT + (size_t)(blockIdx.x >> 5) * 128);
    unsigned old = __hip_atomic_fetch_add(gc, 1u, __ATOMIC_ACQ_REL, __HIP_MEMORY_SCOPE_AGENT);
    if (old == 31u) {
      __hip_atomic_store(gc, 0u, __ATOMIC_RELAXED, __HIP_MEMORY_SCOPE_AGENT);
      unsigned* g2 = (unsigned*)(ws + WS_G2);
      unsigned o2 = __hip_atomic_fetch_add(g2, 1u, __ATOMIC_ACQ_REL, __HIP_MEMORY_SCOPE_AGENT);
      if (o2 == 7u) {
        __hip_atomic_store(g2, 0u, __ATOMIC_RELAXED, __HIP_MEMORY_SCOPE_AGENT);
        __hip_atomic_fetch_add(gen, 1u, __ATOMIC_ACQ_REL, __HIP_MEMORY_SCOPE_AGENT);
      } else {
        do { __builtin_amdgcn_s_sleep(2); }
        while (__hip_atomic_load(gen, __ATOMIC_ACQUIRE, __HIP_MEMORY_SCOPE_AGENT) == g);
      }
    } else {
      do { __builtin_amdgcn_s_sleep(2); }
      while (__hip_atomic_load(gen, __ATOMIC_ACQUIRE, __HIP_MEMORY_SCOPE_AGENT) == g);
    }
    __threadfence();
  }
  __syncthreads();
}

// one GRU hidden unit j: full 1024-dot by one wave, all-lanes result after butterfly
__device__ inline float gru_step(const float* __restrict__ wih,
                                 const float* __restrict__ whh,
                                 int j, int lane,
                                 const float* __restrict__ sx,
                                 const float* __restrict__ sh,
                                 float bi0, float bi1, float bi2,
                                 float bh0, float bh1, float bh2,
                                 float hold) {
  const float* a0 = wih + (size_t)j * HID;
  const float* a1 = wih + (size_t)(HID + j) * HID;
  const float* a2 = wih + (size_t)(2 * HID + j) * HID;
  const float* c0 = whh + (size_t)j * HID;
  const float* c1 = whh + (size_t)(HID + j) * HID;
  const float* c2 = whh + (size_t)(2 * HID + j) * HID;
  float ai0 = 0.f, ai1 = 0.f, ai2 = 0.f, ah0 = 0.f, ah1 = 0.f, ah2 = 0.f;
#pragma unroll
  for (int i = 0; i < 8; ++i) {
    const int e = 2 * lane + 128 * i;
    const float2 xv = *(const float2*)(sx + e);
    const float2 hv = *(const float2*)(sh + e);
    float2 w;
    w = *(const float2*)(a0 + e); ai0 += w.x * xv.x + w.y * xv.y;
    w = *(const float2*)(a1 + e); ai1 += w.x * xv.x + w.y * xv.y;
    w = *(const float2*)(a2 + e); ai2 += w.x * xv.x + w.y * xv.y;
    w = *(const float2*)(c0 + e); ah0 += w.x * hv.x + w.y * hv.y;
    w = *(const float2*)(c1 + e); ah1 += w.x * hv.x + w.y * hv.y;
    w = *(const float2*)(c2 + e); ah2 += w.x * hv.x + w.y * hv.y;
  }
#pragma unroll
  for (int off = 32; off; off >>= 1) {
    ai0 += __shfl_xor(ai0, off); ai1 += __shfl_xor(ai1, off); ai2 += __shfl_xor(ai2, off);
    ah0 += __shfl_xor(ah0, off); ah1 += __shfl_xor(ah1, off); ah2 += __shfl_xor(ah2, off);
  }
  const float r = sigm(ai0 + bi0 + ah0 + bh0);
  const float z = sigm(ai1 + bi1 + ah1 + bh1);
  const float n = tanhf(ai2 + bi2 + r * (ah2 + bh2));
  return (1.f - z) * n + z * hold;
}

__global__ void __launch_bounds__(NTHR)
seq2seq_kernel(const int* __restrict__ X,
               const float* __restrict__ enc_emb,
               const float* __restrict__ enc_wih, const float* __restrict__ enc_whh,
               const float* __restrict__ enc_bih, const float* __restrict__ enc_bhh,
               const float* __restrict__ dec_emb,
               const float* __restrict__ dec_wih, const float* __restrict__ dec_whh,
               const float* __restrict__ dec_bih, const float* __restrict__ dec_bhh,
               const float* __restrict__ lin_w, const float* __restrict__ lin_b,
               float* __restrict__ out, char* __restrict__ ws, int useBf) {
  __shared__ float sx[HID];
  __shared__ float sh[HID];
  __shared__ float slog[128];
  __shared__ float redS[4];
  __shared__ float sbmax;
  __shared__ unsigned long long sball[2];

  const int b = blockIdx.x, tid = threadIdx.x;
  const int q = tid >> 6, lane = tid & 63;
  const int j = 4 * b + q;
  const int vbase = b * RPB;

  unsigned long long* gsum = (unsigned long long*)(ws + WS_GSUM);
  unsigned long long* gkey = (unsigned long long*)(ws + WS_GKEY);
  float* hb = (float*)(ws + WS_HB);
  float* expb = (float*)(ws + WS_EXP);
  unsigned short* linbf = (unsigned short*)(ws + WS_LINBF);
  float* probs = out + (MAX_LEN + 1);

  // per-wave biases for hidden unit j (gates r,z,n stacked at 0,H,2H)
  float ebi0 = enc_bih[j], ebi1 = enc_bih[HID + j], ebi2 = enc_bih[2 * HID + j];
  float ebh0 = enc_bhh[j], ebh1 = enc_bhh[HID + j], ebh2 = enc_bhh[2 * HID + j];
  float dbi0 = dec_bih[j], dbi1 = dec_bih[HID + j], dbi2 = dec_bih[2 * HID + j];
  float dbh0 = dec_bhh[j], dbh1 = dec_bhh[HID + j], dbh2 = dec_bhh[2 * HID + j];

  // ---- P0: SOS token out, lin_w -> bf16 in ws ----
  if (b == 0 && tid == 0) out[0] = 1.0f;  // SOS
  if (useBf) {
    unsigned* dst = (unsigned*)linbf;
    const float2* src = (const float2*)lin_w;
    const size_t npair = (size_t)VOC * HID / 2;
    for (size_t p = (size_t)b * NTHR + tid; p < npair; p += (size_t)NBLK * NTHR) {
      float2 f = src[p];
      dst[p] = (unsigned)f2bf(f.x) | ((unsigned)f2bf(f.y) << 16);
    }
  }
  grid_bar(ws);

  // ---- encoder: 256 sequential GRU steps ----
  for (int t = 0; t < SRC_LEN; ++t) {
    const float* hcur = hb + (t & 1) * HID;
    float* hnext = hb + ((t + 1) & 1) * HID;
    const int tokt = X[t];
    ((float4*)sx)[tid] = ((const float4*)(enc_emb + (size_t)tokt * HID))[tid];
    ((float4*)sh)[tid] = ((const float4*)hcur)[tid];
    __syncthreads();
    const float hold = sh[j];
    const float hnew = gru_step(enc_wih, enc_whh, j, lane, sx, sh,
                                ebi0, ebi1, ebi2, ebh0, ebh1, ebh2, hold);
    if (lane == 0) hnext[j] = hnew;
    grid_bar(ws);
  }

  // ---- greedy decoder ----
  unsigned tok = 1u;   // SOS
  bool done = false;

  for (int t = 0; t <= MAX_LEN; ++t) {
    if (t > 0) {
      // finalize step t-1 (argmax key + sum are globally visible after S2)
      const unsigned long long key = gkey[t - 1];
      const unsigned nxt = 0xFFFFFFFFu - (unsigned)(key & 0xFFFFFFFFull);
      if (b == 0 && tid == 0) out[t] = done ? (float)EOS_TOK : (float)nxt;
      if (tid < RPB) {
        float p = 0.f;
        if (!done) {
          const double s = (double)gsum[t - 1] * (1.0 / 16777216.0);
          p = expb[vbase + tid] * (float)(1.0 / s);
        }
        probs[(size_t)(t - 1) * VOC + vbase + tid] = p;
      }
      if (!done) tok = nxt;
      done = done || (nxt == EOS_TOK);
    }
    if (t == MAX_LEN) break;
    if (done) {
      // all remaining outputs are deterministic: zero prob rows + EOS tokens
      for (int s = t; s < MAX_LEN; ++s) {
        if (tid < RPB) probs[(size_t)s * VOC + vbase + tid] = 0.f;
        if (b == 0 && tid == 0) out[s + 1] = (float)EOS_TOK;
      }
      break;
    }

    // phase A: GRU cell on x = relu(dec_emb[tok])
    const float* hcur = hb + (t & 1) * HID;
    float* hnext = hb + ((t + 1) & 1) * HID;
    {
      float4 f = ((const float4*)(dec_emb + (size_t)tok * HID))[tid];
      f.x = fmaxf(f.x, 0.f); f.y = fmaxf(f.y, 0.f);
      f.z = fmaxf(f.z, 0.f); f.w = fmaxf(f.w, 0.f);
      ((float4*)sx)[tid] = f;
      ((float4*)sh)[tid] = ((const float4*)hcur)[tid];
    }
    __syncthreads();
    const float hold = sh[j];
    const float hnew = gru_step(dec_wih, dec_whh, j, lane, sx, sh,
                                dbi0, dbi1, dbi2, dbh0, dbh1, dbh2, hold);
    if (lane == 0) hnext[j] = hnew;
    grid_bar(ws);   // S1: h_new visible everywhere

    // phase B: logits for this block's 125 vocab rows
    ((float4*)sh)[tid] = ((const float4*)hnext)[tid];
    __syncthreads();
    float hr[16];
#pragma unroll
    for (int i = 0; i < 4; ++i) {
      const float4 f = *(const float4*)(sh + 4 * lane + 256 * i);
      hr[4 * i + 0] = f.x; hr[4 * i + 1] = f.y; hr[4 * i + 2] = f.z; hr[4 * i + 3] = f.w;
    }
    float psum = 0.f;
    for (int v = vbase + q; v < vbase + RPB; v += 4) {
      float acc = 0.f;
      if (useBf) {
        const unsigned long long* wr = (const unsigned long long*)(linbf + (size_t)v * HID);
#pragma unroll
        for (int i = 0; i < 4; ++i) {
          const unsigned long long p = __builtin_nontemporal_load(wr + lane + 64 * i);
          const unsigned lo = (unsigned)p, hi = (unsigned)(p >> 32);
          acc += bflo(lo) * hr[4 * i + 0] + bfhi(lo) * hr[4 * i + 1]
               + bflo(hi) * hr[4 * i + 2] + bfhi(hi) * hr[4 * i + 3];
        }
      } else {
        const float* wr = lin_w + (size_t)v * HID;
#pragma unroll
        for (int i = 0; i < 4; ++i) {
          const float4 f = *(const float4*)(wr + 4 * lane + 256 * i);
          acc += f.x * hr[4 * i + 0] + f.y * hr[4 * i + 1]
               + f.z * hr[4 * i + 2] + f.w * hr[4 * i + 3];
        }
      }
#pragma unroll
      for (int off = 32; off; off >>= 1) acc += __shfl_xor(acc, off);
      if (lane == 0) {
        const float logit = acc + lin_b[v];
        const float e = __expf(logit);
        expb[v] = e;
        psum += e;
        slog[v - vbase] = logit;
      }
    }
    if (lane == 0) redS[q] = psum;
    __syncthreads();
    // block-local max of bf16 logits
    if (q == 0) {
      float m = slog[lane];
      float m2 = (lane + 64 < RPB) ? slog[lane + 64] : -1e30f;
      m = fmaxf(m, m2);
#pragma unroll
      for (int off = 32; off; off >>= 1) m = fmaxf(m, __shfl_xor(m, off));
      if (lane == 0) sbmax = m;
    }
    __syncthreads();
    {
      const bool cand = (tid < RPB) && (slog[tid] >= sbmax - 2e-3f);
      const unsigned long long bal = __ballot(cand);
      if (lane == 0 && q < 2) sball[q] = bal;
    }
    __syncthreads();
    // exact-f32 re-check of candidate rows -> global argmax key
    {
      unsigned long long m0 = sball[0], m1 = sball[1];
      unsigned long long bestk = 0ull;
      int c = 0;
      while (m0 | m1) {
        int r;
        if (m0) { r = __ffsll(m0) - 1; m0 &= m0 - 1; }
        else    { r = 64 + __ffsll(m1) - 1; m1 &= m1 - 1; }
        if ((c & 3) == q) {
          const int v = vbase + r;
          const float* wr = lin_w + (size_t)v * HID;
          float acc = 0.f;
#pragma unroll
          for (int i = 0; i < 4; ++i) {
            const float4 f = *(const float4*)(wr + 4 * lane + 256 * i);
            acc += f.x * hr[4 * i + 0] + f.y * hr[4 * i + 1]
                 + f.z * hr[4 * i + 2] + f.w * hr[4 * i + 3];
          }
#pragma unroll
          for (int off = 32; off; off >>= 1) acc += __shfl_xor(acc, off);
          const float logit = acc + lin_b[v];
          const unsigned u = __float_as_uint(logit);
          const unsigned s = (u & 0x80000000u) ? ~u : (u | 0x80000000u);
          const unsigned long long k =
              ((unsigned long long)s << 32) | (unsigned long long)(0xFFFFFFFFu - (unsigned)v);
          if (k > bestk) bestk = k;
        }
        ++c;
      }
      if (lane == 0 && bestk) atomicMax(&gkey[t], bestk);
    }
    if (tid == 0) {
      const float st = redS[0] + redS[1] + redS[2] + redS[3];
      atomicAdd(&gsum[t], (unsigned long long)((double)st * 16777216.0));
    }
    grid_bar(ws);   // S2: argmax key + sum globally visible
  }
}

extern "C" void kernel_launch(void* const* d_in, const int* in_sizes, int n_in,
                              void* d_out, int out_size, void* d_ws, size_t ws_size,
                              hipStream_t stream) {
  const int* X = (const int*)d_in[0];
  const float* enc_emb = (const float*)d_in[1];
  const float* enc_wih = (const float*)d_in[2];
  const float* enc_whh = (const float*)d_in[3];
  const float* enc_bih = (const float*)d_in[4];
  const float* enc_bhh = (const float*)d_in[5];
  const float* dec_emb = (const float*)d_in[6];
  const float* dec_wih = (const float*)d_in[7];
  const float* dec_whh = (const float*)d_in[8];
  const float* dec_bih = (const float*)d_in[9];
  const float* dec_bhh = (const float*)d_in[10];
  const float* lin_w = (const float*)d_in[11];
  const float* lin_b = (const float*)d_in[12];
  float* out = (float*)d_out;
  char* ws = (char*)d_ws;
  int useBf = (ws_size >= (size_t)WS_NEED_BF) ? 1 : 0;

  hipMemsetAsync(d_ws, 0, WS_ZERO, stream);
  void* args[] = { &X, &enc_emb, &enc_wih, &enc_whh, &enc_bih, &enc_bhh,
                   &dec_emb, &dec_wih, &dec_whh, &dec_bih, &dec_bhh,
                   &lin_w, &lin_b, &out, &ws, &useBf };
  hipLaunchCooperativeKernel((void*)seq2seq_kernel, dim3(NBLK), dim3(NTHR),
                             args, 0, stream);
}

// Round 2
// 4814.516 us; speedup vs baseline: 4.0280x; 4.0280x over previous
//
#include <hip/hip_runtime.h>
#include <stdint.h>

// Seq2seq GRU encoder + greedy GRU decoder, single persistent cooperative kernel.
// R2 changes vs R1:
//  - Fence-free grid barrier: all cross-block state goes through RELAXED
//    agent-scope atomics (coherence-point read/write, no buffer_inv/buffer_wbl2).
//    L1/L2 stay warm -> GRU weights L2-resident across all steps.
//  - Logits matvec on a block-local TRANSPOSED bf16 copy of lin_w:
//    thread-per-row accumulation, coalesced streams, no shuffle chains.

#define HID 1024
#define SRC_LEN 256
#define MAX_LEN 128
#define VOC 32000
#define EOS_TOK 2u

#define NBLK 256
#define NTHR 256
#define RPB 125            // vocab rows per block = 32000/256

// ---- workspace layout (bytes) ----
#define WS_GCNT   0        // 8 group counters, 128B apart
#define WS_G2     1024     // level-2 counter
#define WS_GEN    1152     // generation
#define WS_GSUM   2048     // u64[128] fixed-point softmax sums
#define WS_GKEY   3072     // u64[128] argmax keys
#define WS_HB     4096     // float[2][1024] double-buffered h
#define WS_EXP    12288    // float[32000] exp(logit)   (same-block only)
#define WS_ZERO   12288    // bytes to memset each call
#define WS_LINT   141312   // u64[256 blocks][256 k4][128 r] transposed bf16 lin_w
#define WS_NEED   (141312ull + 256ull * 256ull * 128ull * 8ull)

#define A_SCOPE __HIP_MEMORY_SCOPE_AGENT

__device__ inline unsigned ld_a32(const unsigned* p) {
  return __hip_atomic_load((unsigned*)p, __ATOMIC_RELAXED, A_SCOPE);
}
__device__ inline void st_a32(unsigned* p, unsigned v) {
  __hip_atomic_store(p, v, __ATOMIC_RELAXED, A_SCOPE);
}
__device__ inline unsigned long long ld_a64(const unsigned long long* p) {
  return __hip_atomic_load((unsigned long long*)p, __ATOMIC_RELAXED, A_SCOPE);
}
__device__ inline void st_af(float* p, float v) {
  __hip_atomic_store(p, v, __ATOMIC_RELAXED, A_SCOPE);
}

__device__ inline unsigned short f2bf(float f) {
  unsigned u = __float_as_uint(f);
  unsigned r = ((u >> 16) & 1u) + 0x7FFFu;   // round-to-nearest-even
  return (unsigned short)((u + r) >> 16);
}
__device__ inline float bflo(unsigned u) { return __uint_as_float(u << 16); }
__device__ inline float bfhi(unsigned u) { return __uint_as_float(u & 0xFFFF0000u); }
__device__ inline float sigm(float x) { return 1.0f / (1.0f + __expf(-x)); }

// two-level sense barrier, RELAXED atomics only (no cache maintenance).
// Ordering: __syncthreads() drains vmcnt (agent stores reached coherence point),
// explicit s_waitcnt(0) orders the counter-reset chain.
__device__ inline void grid_bar(char* ws) {
  __syncthreads();
  if (threadIdx.x == 0) {
    __atomic_signal_fence(__ATOMIC_SEQ_CST);
    __builtin_amdgcn_s_waitcnt(0);
    unsigned* gen = (unsigned*)(ws + WS_GEN);
    const unsigned g = ld_a32(gen);
    unsigned* gc = (unsigned*)(ws + WS_GCNT + (size_t)(blockIdx.x >> 5) * 128);
    const unsigned old = __hip_atomic_fetch_add(gc, 1u, __ATOMIC_RELAXED, A_SCOPE);
    if (old == 31u) {
      st_a32(gc, 0u);
      __builtin_amdgcn_s_waitcnt(0);
      unsigned* g2 = (unsigned*)(ws + WS_G2);
      const unsigned o2 = __hip_atomic_fetch_add(g2, 1u, __ATOMIC_RELAXED, A_SCOPE);
      if (o2 == 7u) {
        st_a32(g2, 0u);
        __builtin_amdgcn_s_waitcnt(0);
        __hip_atomic_fetch_add(gen, 1u, __ATOMIC_RELAXED, A_SCOPE);
      } else {
        do { __builtin_amdgcn_s_sleep(4); } while (ld_a32(gen) == g);
      }
    } else {
      do { __builtin_amdgcn_s_sleep(4); } while (ld_a32(gen) == g);
    }
    __atomic_signal_fence(__ATOMIC_SEQ_CST);
  }
  __syncthreads();
}

// stage 4KB h vector from ws into LDS via coherent u64 loads
__device__ inline void load_h_lds(float* dst, const float* src, int tid) {
  const unsigned long long* s = (const unsigned long long*)src;
  unsigned long long* d = (unsigned long long*)dst;
  const unsigned long long a = ld_a64(s + 2 * tid);
  const unsigned long long b = ld_a64(s + 2 * tid + 1);
  d[2 * tid] = a;
  d[2 * tid + 1] = b;
}

// one GRU hidden unit j: full 1024-dot by one wave, all-lanes result after butterfly
__device__ inline float gru_step(const float* __restrict__ wih,
                                 const float* __restrict__ whh,
                                 int j, int lane,
                                 const float* __restrict__ sx,
                                 const float* __restrict__ sh,
                                 float bi0, float bi1, float bi2,
                                 float bh0, float bh1, float bh2,
                                 float hold) {
  const float* a0 = wih + (size_t)j * HID;
  const float* a1 = wih + (size_t)(HID + j) * HID;
  const float* a2 = wih + (size_t)(2 * HID + j) * HID;
  const float* c0 = whh + (size_t)j * HID;
  const float* c1 = whh + (size_t)(HID + j) * HID;
  const float* c2 = whh + (size_t)(2 * HID + j) * HID;
  float ai0 = 0.f, ai1 = 0.f, ai2 = 0.f, ah0 = 0.f, ah1 = 0.f, ah2 = 0.f;
#pragma unroll
  for (int i = 0; i < 8; ++i) {
    const int e = 2 * lane + 128 * i;
    const float2 xv = *(const float2*)(sx + e);
    const float2 hv = *(const float2*)(sh + e);
    float2 w;
    w = *(const float2*)(a0 + e); ai0 += w.x * xv.x + w.y * xv.y;
    w = *(const float2*)(a1 + e); ai1 += w.x * xv.x + w.y * xv.y;
    w = *(const float2*)(a2 + e); ai2 += w.x * xv.x + w.y * xv.y;
    w = *(const float2*)(c0 + e); ah0 += w.x * hv.x + w.y * hv.y;
    w = *(const float2*)(c1 + e); ah1 += w.x * hv.x + w.y * hv.y;
    w = *(const float2*)(c2 + e); ah2 += w.x * hv.x + w.y * hv.y;
  }
#pragma unroll
  for (int off = 32; off; off >>= 1) {
    ai0 += __shfl_xor(ai0, off); ai1 += __shfl_xor(ai1, off); ai2 += __shfl_xor(ai2, off);
    ah0 += __shfl_xor(ah0, off); ah1 += __shfl_xor(ah1, off); ah2 += __shfl_xor(ah2, off);
  }
  const float r = sigm(ai0 + bi0 + ah0 + bh0);
  const float z = sigm(ai1 + bi1 + ah1 + bh1);
  const float n = tanhf(ai2 + bi2 + r * (ah2 + bh2));
  return (1.f - z) * n + z * hold;
}

__global__ void __launch_bounds__(NTHR)
seq2seq_kernel(const int* __restrict__ X,
               const float* __restrict__ enc_emb,
               const float* __restrict__ enc_wih, const float* __restrict__ enc_whh,
               const float* __restrict__ enc_bih, const float* __restrict__ enc_bhh,
               const float* __restrict__ dec_emb,
               const float* __restrict__ dec_wih, const float* __restrict__ dec_whh,
               const float* __restrict__ dec_bih, const float* __restrict__ dec_bhh,
               const float* __restrict__ lin_w, const float* __restrict__ lin_b,
               float* __restrict__ out, char* __restrict__ ws, int useBf) {
  __shared__ float sx[HID];
  __shared__ float sh[HID];
  __shared__ float spart[256];
  __shared__ float slog[128];
  __shared__ float redS[4];
  __shared__ float sbmax;
  __shared__ unsigned long long sball[2];

  const int b = blockIdx.x, tid = threadIdx.x;
  const int q = tid >> 6, lane = tid & 63;
  const int j = 4 * b + q;
  const int vbase = b * RPB;

  unsigned long long* gsum = (unsigned long long*)(ws + WS_GSUM);
  unsigned long long* gkey = (unsigned long long*)(ws + WS_GKEY);
  float* hb = (float*)(ws + WS_HB);
  float* expb = (float*)(ws + WS_EXP);
  unsigned long long* lint = (unsigned long long*)(ws + WS_LINT);
  float* probs = out + (MAX_LEN + 1);

  // per-wave biases for hidden unit j (gates r,z,n stacked at 0,H,2H)
  float ebi0 = enc_bih[j], ebi1 = enc_bih[HID + j], ebi2 = enc_bih[2 * HID + j];
  float ebh0 = enc_bhh[j], ebh1 = enc_bhh[HID + j], ebh2 = enc_bhh[2 * HID + j];
  float dbi0 = dec_bih[j], dbi1 = dec_bih[HID + j], dbi2 = dec_bih[2 * HID + j];
  float dbh0 = dec_bhh[j], dbh1 = dec_bhh[HID + j], dbh2 = dec_bhh[2 * HID + j];

  if (b == 0 && tid == 0) out[0] = 1.0f;  // SOS

  // ---- P0: block-local transposed bf16 copy of this block's 125 lin_w rows ----
  // layout: lint[b][k4][r] u64 = 4 bf16 (k = 4*k4..4*k4+3) of row vbase+r.
  // writer block == reader block -> plain loads in phase B are coherent.
  if (useBf) {
    unsigned long long* dst = lint + ((size_t)b << 15);
    for (int i = 0; i < 128; ++i) {
      const int g = i * NTHR + tid;          // 0..32767
      const int r = g & 127, k4 = g >> 7;    // k4 0..255
      unsigned long long w = 0ull;
      if (r < RPB) {
        const float4 f = *(const float4*)(lin_w + (size_t)(vbase + r) * HID + 4 * k4);
        w = (unsigned long long)f2bf(f.x)
          | ((unsigned long long)f2bf(f.y) << 16)
          | ((unsigned long long)f2bf(f.z) << 32)
          | ((unsigned long long)f2bf(f.w) << 48);
      }
      dst[g] = w;
    }
  }
  grid_bar(ws);

  // ---- encoder: 256 sequential GRU steps ----
  for (int t = 0; t < SRC_LEN; ++t) {
    const float* hcur = hb + (t & 1) * HID;
    float* hnext = hb + ((t + 1) & 1) * HID;
    const int tokt = X[t];
    ((float4*)sx)[tid] = ((const float4*)(enc_emb + (size_t)tokt * HID))[tid];
    load_h_lds(sh, hcur, tid);
    __syncthreads();
    const float hold = sh[j];
    const float hnew = gru_step(enc_wih, enc_whh, j, lane, sx, sh,
                                ebi0, ebi1, ebi2, ebh0, ebh1, ebh2, hold);
    if (lane == 0) st_af(&hnext[j], hnew);
    grid_bar(ws);
  }

  // ---- greedy decoder ----
  unsigned tok = 1u;   // SOS
  bool done = false;

  for (int t = 0; t <= MAX_LEN; ++t) {
    if (t > 0) {
      const unsigned long long key = ld_a64(&gkey[t - 1]);
      const unsigned nxt = 0xFFFFFFFFu - (unsigned)(key & 0xFFFFFFFFull);
      if (b == 0 && tid == 0) out[t] = done ? (float)EOS_TOK : (float)nxt;
      if (tid < RPB) {
        float p = 0.f;
        if (!done) {
          const unsigned long long sraw = ld_a64(&gsum[t - 1]);
          const double s = (double)sraw * (1.0 / 16777216.0);
          p = expb[vbase + tid] * (float)(1.0 / s);
        }
        probs[(size_t)(t - 1) * VOC + vbase + tid] = p;
      }
      if (!done) tok = nxt;
      done = done || (nxt == EOS_TOK);
    }
    if (t == MAX_LEN) break;
    if (done) {
      for (int s = t; s < MAX_LEN; ++s) {
        if (tid < RPB) probs[(size_t)s * VOC + vbase + tid] = 0.f;
        if (b == 0 && tid == 0) out[s + 1] = (float)EOS_TOK;
      }
      break;
    }

    // ---- phase A: GRU cell on x = relu(dec_emb[tok]) ----
    const float* hcur = hb + (t & 1) * HID;
    float* hnext = hb + ((t + 1) & 1) * HID;
    {
      float4 f = ((const float4*)(dec_emb + (size_t)tok * HID))[tid];
      f.x = fmaxf(f.x, 0.f); f.y = fmaxf(f.y, 0.f);
      f.z = fmaxf(f.z, 0.f); f.w = fmaxf(f.w, 0.f);
      ((float4*)sx)[tid] = f;
    }
    load_h_lds(sh, hcur, tid);
    __syncthreads();
    const float hold = sh[j];
    const float hnew = gru_step(dec_wih, dec_whh, j, lane, sx, sh,
                                dbi0, dbi1, dbi2, dbh0, dbh1, dbh2, hold);
    if (lane == 0) st_af(&hnext[j], hnew);
    grid_bar(ws);   // S1: h_new visible everywhere

    // ---- phase B: logits for this block's 125 vocab rows ----
    load_h_lds(sh, hnext, tid);
    if (tid < 128) slog[tid] = -1e30f;
    __syncthreads();

    if (useBf) {
      // thread-per-row over half of k: coalesced u64 stream, LDS-broadcast h
      const int r = tid & 127, khalf = tid >> 7;
      const unsigned long long* wp = lint + ((size_t)b << 15)
                                   + ((size_t)khalf << 14) + (size_t)r;
      const float* hp = sh + (khalf << 9);
      float acc = 0.f;
#pragma unroll 8
      for (int k4 = 0; k4 < 128; ++k4) {
        const unsigned long long w = wp[(size_t)k4 << 7];
        const float4 hv = *(const float4*)(hp + (k4 << 2));
        const unsigned lo = (unsigned)w, hi = (unsigned)(w >> 32);
        acc += bflo(lo) * hv.x + bfhi(lo) * hv.y
             + bflo(hi) * hv.z + bfhi(hi) * hv.w;
      }
      spart[tid] = acc;
      __syncthreads();
      float e = 0.f;
      if (tid < RPB) {
        const float logit = spart[tid] + spart[tid + 128] + lin_b[vbase + tid];
        e = __expf(logit);
        expb[vbase + tid] = e;
        slog[tid] = logit;
      }
      float s = e;
#pragma unroll
      for (int off = 32; off; off >>= 1) s += __shfl_xor(s, off);
      if (lane == 0) redS[q] = s;
      __syncthreads();
    } else {
      // fallback: f32 row-per-wave from lin_w
      float psum = 0.f;
      for (int v = vbase + q; v < vbase + RPB; v += 4) {
        const float* wr = lin_w + (size_t)v * HID;
        float acc = 0.f;
#pragma unroll
        for (int i = 0; i < 4; ++i) {
          const float4 f = *(const float4*)(wr + 4 * lane + 256 * i);
          const float4 hv = *(const float4*)(sh + 4 * lane + 256 * i);
          acc += f.x * hv.x + f.y * hv.y + f.z * hv.z + f.w * hv.w;
        }
#pragma unroll
        for (int off = 32; off; off >>= 1) acc += __shfl_xor(acc, off);
        if (lane == 0) {
          const float logit = acc + lin_b[v];
          const float e = __expf(logit);
          expb[v] = e;
          psum += e;
          slog[v - vbase] = logit;
        }
      }
      if (lane == 0) redS[q] = psum;
      __syncthreads();
    }

    // block-local max of approx logits
    if (q == 0) {
      float m = fmaxf(slog[lane], slog[lane + 64]);
#pragma unroll
      for (int off = 32; off; off >>= 1) m = fmaxf(m, __shfl_xor(m, off));
      if (lane == 0) sbmax = m;
    }
    __syncthreads();
    {
      const bool cand = (tid < RPB) && (slog[tid] >= sbmax - 2e-3f);
      const unsigned long long bal = __ballot(cand);
      if (lane == 0 && q < 2) sball[q] = bal;
    }
    __syncthreads();
    // exact-f32 re-check of candidate rows -> global argmax key
    {
      unsigned long long m0 = sball[0], m1 = sball[1];
      unsigned long long bestk = 0ull;
      int c = 0;
      while (m0 | m1) {
        int r;
        if (m0) { r = __ffsll(m0) - 1; m0 &= m0 - 1; }
        else    { r = 64 + __ffsll(m1) - 1; m1 &= m1 - 1; }
        if ((c & 3) == q) {
          const int v = vbase + r;
          const float* wr = lin_w + (size_t)v * HID;
          float acc = 0.f;
#pragma unroll
          for (int i = 0; i < 4; ++i) {
            const float4 f = *(const float4*)(wr + 4 * lane + 256 * i);
            const float4 hv = *(const float4*)(sh + 4 * lane + 256 * i);
            acc += f.x * hv.x + f.y * hv.y + f.z * hv.z + f.w * hv.w;
          }
#pragma unroll
          for (int off = 32; off; off >>= 1) acc += __shfl_xor(acc, off);
          const float logit = acc + lin_b[v];
          const unsigned u = __float_as_uint(logit);
          const unsigned s = (u & 0x80000000u) ? ~u : (u | 0x80000000u);
          const unsigned long long k =
              ((unsigned long long)s << 32) | (unsigned long long)(0xFFFFFFFFu - (unsigned)v);
          if (k > bestk) bestk = k;
        }
        ++c;
      }
      if (lane == 0 && bestk) atomicMax(&gkey[t], bestk);
    }
    if (tid == 0) {
      const float st = redS[0] + redS[1] + redS[2] + redS[3];
      atomicAdd(&gsum[t], (unsigned long long)((double)st * 16777216.0));
    }
    grid_bar(ws);   // S2: argmax key + sum globally visible
  }
}

extern "C" void kernel_launch(void* const* d_in, const int* in_sizes, int n_in,
                              void* d_out, int out_size, void* d_ws, size_t ws_size,
                              hipStream_t stream) {
  const int* X = (const int*)d_in[0];
  const float* enc_emb = (const float*)d_in[1];
  const float* enc_wih = (const float*)d_in[2];
  const float* enc_whh = (const float*)d_in[3];
  const float* enc_bih = (const float*)d_in[4];
  const float* enc_bhh = (const float*)d_in[5];
  const float* dec_emb = (const float*)d_in[6];
  const float* dec_wih = (const float*)d_in[7];
  const float* dec_whh = (const float*)d_in[8];
  const float* dec_bih = (const float*)d_in[9];
  const float* dec_bhh = (const float*)d_in[10];
  const float* lin_w = (const float*)d_in[11];
  const float* lin_b = (const float*)d_in[12];
  float* out = (float*)d_out;
  char* ws = (char*)d_ws;
  int useBf = (ws_size >= (size_t)WS_NEED) ? 1 : 0;

  hipMemsetAsync(d_ws, 0, WS_ZERO, stream);
  void* args[] = { &X, &enc_emb, &enc_wih, &enc_whh, &enc_bih, &enc_bhh,
                   &dec_emb, &dec_wih, &dec_whh, &dec_bih, &dec_bhh,
                   &lin_w, &lin_b, &out, &ws, &useBf };
  hipLaunchCooperativeKernel((void*)seq2seq_kernel, dim3(NBLK), dim3(NTHR),
                             args, 0, stream);
}